// Round 1
// baseline (214.405 us; speedup 1.0000x reference)
//
#include <hip/hip_runtime.h>
#include <math.h>

// Problem constants
#define D 256
#define H 8
#define HD 32
#define S 255
#define S1 256
#define B 4

// Workspace layout (float offsets)
#define WS_Q      0          // [B*S1][D] = 262144
#define WS_K      262144     // [B*S1][D]
#define WS_V      524288     // [B*S1][D]
#define WS_AP     786432     // [B*S][D] A' = desc@W1a.T + eb1   (261120, reserve 262144)
#define WS_BP     1048576    // [B*S][D] B' = desc@W1b.T
#define WS_BT     1310720    // [B][D(k)][S1(j0)]  B' transposed, j pad col = 0
#define WS_CT     1572864    // [B][D(k)][S1(j0)]  (A'+B') transposed
#define WS_MT     1835008    // [D(k)][H]  = 2048
#define WS_CH     1837056    // [H]
#define WS_QLOG   1837064    // [B][H][S1] = 8192
#define WS_KLOG   1845256    // [B][H][S1] = 8192
// total ~1853448 floats ~ 7.5 MB

// ---------------------------------------------------------------------------
// Kernel 1: fused 5-job tiled fp32 GEMM  out = X @ W.T + bias
// jobs: 0:q 1:k 2:v (X=nve, 1024 rows)  3:A' 4:B' (X=desc, 1020 rows)
// ---------------------------------------------------------------------------
#define GT_K 16

__global__ __launch_bounds__(256) void gemm5(
    const float* __restrict__ desc, const float* __restrict__ nve,
    const float* __restrict__ qW, const float* __restrict__ qb,
    const float* __restrict__ kW, const float* __restrict__ kb,
    const float* __restrict__ vW, const float* __restrict__ vb,
    const float* __restrict__ eW1, const float* __restrict__ eb1,
    float* __restrict__ ws)
{
    int job = blockIdx.z;
    const float* X; const float* W; const float* bias; float* out;
    int rows, wstride, woff;
    switch (job) {
      case 0: X=nve;  W=qW;  bias=qb;  out=ws+WS_Q;  rows=1024; wstride=256; woff=0;   break;
      case 1: X=nve;  W=kW;  bias=kb;  out=ws+WS_K;  rows=1024; wstride=256; woff=0;   break;
      case 2: X=nve;  W=vW;  bias=vb;  out=ws+WS_V;  rows=1024; wstride=256; woff=0;   break;
      case 3: X=desc; W=eW1; bias=eb1; out=ws+WS_AP; rows=1020; wstride=512; woff=0;   break;
      default:X=desc; W=eW1; bias=0;   out=ws+WS_BP; rows=1020; wstride=512; woff=256; break;
    }
    __shared__ float Xs[GT_K][64+4];
    __shared__ float Ws[GT_K][64+4];
    int tid = threadIdx.x;
    int mBase = blockIdx.x * 64;
    int nBase = blockIdx.y * 64;
    int tm = tid >> 4;   // 0..15
    int tn = tid & 15;   // 0..15
    float acc[4][4] = {};
    for (int k0 = 0; k0 < 256; k0 += GT_K) {
        #pragma unroll
        for (int t = 0; t < 4; t++) {
            int idx = tid + t*256;       // 0..1023
            int mm = idx >> 4, kk = idx & 15;
            int row = mBase + mm;
            Xs[kk][mm] = (row < rows) ? X[row*256 + k0 + kk] : 0.f;
            int cc = nBase + mm;
            Ws[kk][mm] = W[cc*wstride + woff + k0 + kk];
        }
        __syncthreads();
        #pragma unroll
        for (int kk = 0; kk < GT_K; kk++) {
            float a[4], bv[4];
            #pragma unroll
            for (int u = 0; u < 4; u++) a[u]  = Xs[kk][tm*4+u];
            #pragma unroll
            for (int u = 0; u < 4; u++) bv[u] = Ws[kk][tn*4+u];
            #pragma unroll
            for (int x = 0; x < 4; x++)
                #pragma unroll
                for (int y = 0; y < 4; y++)
                    acc[x][y] = fmaf(a[x], bv[y], acc[x][y]);
        }
        __syncthreads();
    }
    #pragma unroll
    for (int x = 0; x < 4; x++) {
        int row = mBase + tm*4 + x;
        if (row < rows) {
            #pragma unroll
            for (int y = 0; y < 4; y++) {
                int c = nBase + tn*4 + y;
                float bvv = bias ? bias[c] : 0.f;
                out[row*256 + c] = acc[x][y] + bvv;
            }
        }
    }
}

// ---------------------------------------------------------------------------
// Kernel 2: transpose/combine:  Bt[b][k][j] = B'[b][j][k];  Ct = (A'+B')^T
// pad column j=255 -> 0
// ---------------------------------------------------------------------------
__global__ __launch_bounds__(256) void transpose_combine(float* __restrict__ ws)
{
    const float* Ap = ws + WS_AP;
    const float* Bp = ws + WS_BP;
    float* Bt = ws + WS_BT;
    float* Ct = ws + WS_CT;
    int b  = blockIdx.z;
    int j0 = blockIdx.x * 32;
    int k0 = blockIdx.y * 32;
    __shared__ float tA[32][33], tB[32][33];
    int tid = threadIdx.x;
    int lr = tid >> 5;    // 0..7
    int lc = tid & 31;    // 0..31
    #pragma unroll
    for (int t = 0; t < 4; t++) {
        int jj = lr + t*8;
        int j = j0 + jj;
        float av = 0.f, bv = 0.f;
        if (j < S) {
            av = Ap[(b*S + j)*256 + k0 + lc];
            bv = Bp[(b*S + j)*256 + k0 + lc];
        }
        tA[jj][lc] = av;
        tB[jj][lc] = bv;
    }
    __syncthreads();
    #pragma unroll
    for (int t = 0; t < 4; t++) {
        int kk = lr + t*8;
        int k = k0 + kk;
        int j = j0 + lc;
        float av = tA[lc][kk];
        float bv = tB[lc][kk];
        Bt[(b*256 + k)*256 + j] = bv;
        Ct[(b*256 + k)*256 + j] = av + bv;
    }
}

// ---------------------------------------------------------------------------
// Kernel 3: prep small:  Mt[k][h] = sum_hd we[hd]*eW2[h*32+hd][k],
//                        ch[h] = sum_hd we[hd]*eb2[h*32+hd],
//                        qlog[b][h][t] = q[b,t]·wq_h,  klog = k[b,t]·wk_h
// ---------------------------------------------------------------------------
__global__ __launch_bounds__(256) void prep_small(
    const float* __restrict__ eW2, const float* __restrict__ eb2,
    const float* __restrict__ aW, float* __restrict__ ws)
{
    int blk = blockIdx.x;
    int tid = threadIdx.x;
    if (blk < 8) {
        int h = blk;
        float acc = 0.f;
        #pragma unroll
        for (int hd = 0; hd < 32; hd++)
            acc = fmaf(aW[64+hd], eW2[(h*32+hd)*256 + tid], acc);
        ws[WS_MT + tid*8 + h] = acc;
        if (tid == 0) {
            float c = 0.f;
            for (int hd = 0; hd < 32; hd++) c = fmaf(aW[64+hd], eb2[h*32+hd], c);
            ws[WS_CH + h] = c;
        }
    } else {
        int b = blk - 8;
        int t = tid;
        const float* q  = ws + WS_Q;
        const float* kk = ws + WS_K;
        #pragma unroll
        for (int h = 0; h < 8; h++) {
            float aq = 0.f, ak = 0.f;
            #pragma unroll
            for (int d = 0; d < 32; d++) {
                aq = fmaf(q [(b*256+t)*256 + h*32+d], aW[d],    aq);
                ak = fmaf(kk[(b*256+t)*256 + h*32+d], aW[32+d], ak);
            }
            ws[WS_QLOG + (b*8+h)*256 + t] = aq;
            ws[WS_KLOG + (b*8+h)*256 + t] = ak;
        }
    }
}

// ---------------------------------------------------------------------------
// Kernel 4: main — per (b,i) row: edge LN+ReLU+head-dot, softmax, ctx
// ---------------------------------------------------------------------------
__global__ __launch_bounds__(256) void main_kernel(
    const float* __restrict__ ln_g, const float* __restrict__ ln_b,
    const float* __restrict__ ab, const float* __restrict__ ws,
    float* __restrict__ out)
{
    int b = blockIdx.y;
    int i = blockIdx.x;
    int tid = threadIdx.x;

    __shared__ float agb[256][4];     // {a_k, g_k, beta_k, pad} per k, 16B rows
    __shared__ float MtL[2048];       // [k][h]
    __shared__ float PL[8][256];      // logits -> p
    __shared__ float mx[8], sm[8];

    const float* Ap   = ws + WS_AP;
    const float* Bt   = ws + WS_BT;
    const float* Ct   = ws + WS_CT;
    const float* Mt   = ws + WS_MT;
    const float* chp  = ws + WS_CH;
    const float* qlog = ws + WS_QLOG;
    const float* klog = ws + WS_KLOG;

    // stage per-k uniforms
    float aval = 0.f;
    if (i >= 1) aval = Ap[(b*S + (i-1))*256 + tid];
    agb[tid][0] = aval;
    agb[tid][1] = ln_g[tid];
    agb[tid][2] = ln_b[tid];
    agb[tid][3] = 0.f;
    #pragma unroll
    for (int t = 0; t < 8; t++) MtL[tid + t*256] = Mt[tid + t*256];
    __syncthreads();

    const float* colBase = ((i >= 1) ? Bt : Ct) + b*65536;
    int m = tid - 1;
    float acc[8] = {0,0,0,0,0,0,0,0};

    if (tid >= 1) {
        // pass 1: stats
        float s = 0.f, s2 = 0.f;
        #pragma unroll 8
        for (int k = 0; k < 256; k++) {
            float t0 = colBase[k*256 + m] + agb[k][0];
            s += t0;
            s2 = fmaf(t0, t0, s2);
        }
        float mu  = s  * (1.0f/256.0f);
        float var = s2 * (1.0f/256.0f) - mu*mu;
        float inv = rsqrtf(var + 1e-5f);
        float mus = mu * inv;
        // pass 2: normalized relu dot with M (8 heads)
        #pragma unroll 4
        for (int k = 0; k < 256; k++) {
            float4 u = *(const float4*)&agb[k][0];   // a, g, beta
            float t0 = colBase[k*256 + m] + u.x;
            float ig = inv * u.y;
            float C  = fmaf(-mus, u.y, u.z);
            float w  = fmaf(t0, ig, C);
            w = fmaxf(w, 0.f);
            float4 m0 = *(const float4*)&MtL[k*8];
            float4 m1 = *(const float4*)&MtL[k*8 + 4];
            acc[0] = fmaf(w, m0.x, acc[0]);
            acc[1] = fmaf(w, m0.y, acc[1]);
            acc[2] = fmaf(w, m0.z, acc[2]);
            acc[3] = fmaf(w, m0.w, acc[3]);
            acc[4] = fmaf(w, m1.x, acc[4]);
            acc[5] = fmaf(w, m1.y, acc[5]);
            acc[6] = fmaf(w, m1.z, acc[6]);
            acc[7] = fmaf(w, m1.w, acc[7]);
        }
    }

    // logits
    float abv = ab[0];
    #pragma unroll
    for (int h = 0; h < 8; h++) {
        float base = qlog[(b*8+h)*256 + i] + klog[(b*8+h)*256 + tid] + abv;
        float l;
        if (tid == 0) l = base - 1e9f;                  // masked column j=0
        else          l = base + acc[h] + chp[h];
        PL[h][tid] = l;
    }
    __syncthreads();

    // max per head
    {
        int h = tid >> 5, s = tid & 31;
        float mval = -INFINITY;
        #pragma unroll
        for (int r = 0; r < 8; r++) mval = fmaxf(mval, PL[h][s + r*32]);
        #pragma unroll
        for (int off = 16; off >= 1; off >>= 1)
            mval = fmaxf(mval, __shfl_xor(mval, off, 64));
        if (s == 0) mx[h] = mval;
    }
    __syncthreads();

    // exp
    float p[8];
    #pragma unroll
    for (int h = 0; h < 8; h++) p[h] = expf(PL[h][tid] - mx[h]);
    __syncthreads();   // everyone done reading logits
    #pragma unroll
    for (int h = 0; h < 8; h++) PL[h][tid] = p[h];
    __syncthreads();

    // sum per head
    {
        int h = tid >> 5, s = tid & 31;
        float sv = 0.f;
        #pragma unroll
        for (int r = 0; r < 8; r++) sv += PL[h][s + r*32];
        #pragma unroll
        for (int off = 16; off >= 1; off >>= 1)
            sv += __shfl_xor(sv, off, 64);
        if (s == 0) sm[h] = sv;
    }
    __syncthreads();

    // attn output
    float* attnOut = out + B*S1*D;   // 262144
    #pragma unroll
    for (int h = 0; h < 8; h++) {
        float a = p[h] / sm[h];
        attnOut[((b*8+h)*256 + i)*256 + tid] = a;
    }

    // ctx: thread (h = tid>>5, d = tid&31) computes basis[b][i][h*32+d]
    {
        int h = tid >> 5;
        const float* v = ws + WS_V + b*65536;
        float rs = 1.0f / sm[h];
        float cacc = 0.f;
        #pragma unroll 4
        for (int jj = 0; jj < 256; jj++)
            cacc = fmaf(PL[h][jj], v[jj*256 + tid], cacc);
        out[(b*256 + i)*256 + tid] = cacc * rs;
    }
}

// ---------------------------------------------------------------------------
extern "C" void kernel_launch(void* const* d_in, const int* in_sizes, int n_in,
                              void* d_out, int out_size, void* d_ws, size_t ws_size,
                              hipStream_t stream)
{
    const float* desc = (const float*)d_in[0];
    const float* nve  = (const float*)d_in[1];
    const float* qW   = (const float*)d_in[2];
    const float* qb   = (const float*)d_in[3];
    const float* kW   = (const float*)d_in[4];
    const float* kb   = (const float*)d_in[5];
    const float* vW   = (const float*)d_in[6];
    const float* vb   = (const float*)d_in[7];
    const float* eW1  = (const float*)d_in[8];
    const float* eb1  = (const float*)d_in[9];
    const float* ln_g = (const float*)d_in[10];
    const float* ln_b = (const float*)d_in[11];
    const float* eW2  = (const float*)d_in[12];
    const float* eb2  = (const float*)d_in[13];
    const float* aW   = (const float*)d_in[14];
    const float* ab   = (const float*)d_in[15];
    float* ws  = (float*)d_ws;
    float* out = (float*)d_out;

    gemm5<<<dim3(16, 4, 5), 256, 0, stream>>>(desc, nve, qW, qb, kW, kb, vW, vb, eW1, eb1, ws);
    transpose_combine<<<dim3(8, 8, 4), 256, 0, stream>>>(ws);
    prep_small<<<dim3(12), 256, 0, stream>>>(eW2, eb2, aW, ws);
    main_kernel<<<dim3(256, 4), 256, 0, stream>>>(ln_g, ln_b, ab, ws, out);
}

// Round 2
// 181.568 us; speedup vs baseline: 1.1809x; 1.1809x over previous
//
#include <hip/hip_runtime.h>
#include <math.h>

#define D 256
#define H 8
#define HD 32
#define S 255
#define S1 256
#define B 4

// Workspace layout (float offsets)
#define WS_Q      0          // [B*S1][256]
#define WS_K      262144
#define WS_V      524288
#define WS_AP     786432     // [B*S][256] A' = desc@W1a.T + eb1
#define WS_BP     1048576    // [B*S][256] B' = desc@W1b.T
#define WS_BT     1310720    // [B][256 k][256 j]  B'^T (col j = B' row j, col 255 = 0)
#define WS_CT     1572864    // [B][256 k][256 j]  (A'+B')^T
#define WS_G      1835008    // [B][256][256]  G[i][j] = A'[i]·B'[j]  (i,j<255 valid)
#define WS_MT     2097152    // [256 k][8 h]
#define WS_CH     2099200    // [8]
#define WS_QLOG   2099264    // [B][H][256]
#define WS_KLOG   2107456    // [B][H][256]
#define WS_SA     2115648    // [B][256] row sums of A'
#define WS_QA     2116672    // [B][256] row sumsq of A'
#define WS_SB     2117696
#define WS_QB     2118720
// end: 2119744 floats (~8.5 MB)

// ---------------------------------------------------------------------------
// Generic 64x64 fp32 tile GEMM, 512 threads: out[r][c] = X[r,:]·W[c,:] + bias
// X: [xRows][256] stride 256.  W row c at W[c*wStride + wOff + k].
// ---------------------------------------------------------------------------
__device__ __forceinline__ void gemm_tile_512(
    const float* __restrict__ X, int xRows,
    const float* __restrict__ W, int wStride, int wOff, int wRows,
    const float* __restrict__ bias,
    float* __restrict__ out, int oStride, int oRows, int oCols,
    int mBase, int nBase)
{
    __shared__ float Xst[32][68];   // [k][row], stride 68 -> 16B-aligned rows
    __shared__ float Wst[32][68];   // [k][col]
    int tid = threadIdx.x;
    int r  = tid >> 3;      // 0..63
    int kq = tid & 7;       // k-quad
    int tm = tid >> 4;      // 0..31 -> rows tm*2+{0,1}
    int tn = tid & 15;      // 0..15 -> cols tn*4+{0..3}
    float acc[2][4] = {};
    for (int k0 = 0; k0 < 256; k0 += 32) {
        __syncthreads();
        float4 xv = make_float4(0.f,0.f,0.f,0.f);
        float4 wv = make_float4(0.f,0.f,0.f,0.f);
        int xr = mBase + r;
        if (xr < xRows) xv = *(const float4*)&X[xr*256 + k0 + kq*4];
        int wr = nBase + r;
        if (wr < wRows) wv = *(const float4*)&W[wr*wStride + wOff + k0 + kq*4];
        Xst[kq*4+0][r] = xv.x; Xst[kq*4+1][r] = xv.y;
        Xst[kq*4+2][r] = xv.z; Xst[kq*4+3][r] = xv.w;
        Wst[kq*4+0][r] = wv.x; Wst[kq*4+1][r] = wv.y;
        Wst[kq*4+2][r] = wv.z; Wst[kq*4+3][r] = wv.w;
        __syncthreads();
        #pragma unroll 8
        for (int kk = 0; kk < 32; kk++) {
            float2 a2 = *(const float2*)&Xst[kk][tm*2];
            float4 b4 = *(const float4*)&Wst[kk][tn*4];
            acc[0][0] = fmaf(a2.x, b4.x, acc[0][0]);
            acc[0][1] = fmaf(a2.x, b4.y, acc[0][1]);
            acc[0][2] = fmaf(a2.x, b4.z, acc[0][2]);
            acc[0][3] = fmaf(a2.x, b4.w, acc[0][3]);
            acc[1][0] = fmaf(a2.y, b4.x, acc[1][0]);
            acc[1][1] = fmaf(a2.y, b4.y, acc[1][1]);
            acc[1][2] = fmaf(a2.y, b4.z, acc[1][2]);
            acc[1][3] = fmaf(a2.y, b4.w, acc[1][3]);
        }
    }
    int cbase = nBase + tn*4;
    float4 bv = make_float4(0.f,0.f,0.f,0.f);
    if (bias && cbase < oCols) bv = *(const float4*)&bias[cbase];
    #pragma unroll
    for (int x = 0; x < 2; x++) {
        int rr = mBase + tm*2 + x;
        if (rr >= oRows) continue;
        if (cbase + 3 < oCols) {
            float4 o;
            o.x = acc[x][0] + bv.x; o.y = acc[x][1] + bv.y;
            o.z = acc[x][2] + bv.z; o.w = acc[x][3] + bv.w;
            *(float4*)&out[rr*oStride + cbase] = o;
        } else {
            float bb[4] = {bv.x, bv.y, bv.z, bv.w};
            for (int y = 0; y < 4; y++)
                if (cbase + y < oCols) out[rr*oStride + cbase + y] = acc[x][y] + bb[y];
        }
    }
}

// ---------------------------------------------------------------------------
// Kernel 1: q,k,v,A',B' GEMMs.  grid (16,4,5)
// ---------------------------------------------------------------------------
__global__ __launch_bounds__(512, 4) void gemm_qkvAB(
    const float* __restrict__ desc, const float* __restrict__ nve,
    const float* __restrict__ qW, const float* __restrict__ qb,
    const float* __restrict__ kW, const float* __restrict__ kb,
    const float* __restrict__ vW, const float* __restrict__ vb,
    const float* __restrict__ eW1, const float* __restrict__ eb1,
    float* __restrict__ ws)
{
    int job = blockIdx.z;
    const float *X, *W, *bias; float* out; int xRows, wStride, wOff;
    switch (job) {
      case 0: X=nve;  W=qW;  bias=qb;      out=ws+WS_Q;  xRows=1024; wStride=256; wOff=0;   break;
      case 1: X=nve;  W=kW;  bias=kb;      out=ws+WS_K;  xRows=1024; wStride=256; wOff=0;   break;
      case 2: X=nve;  W=vW;  bias=vb;      out=ws+WS_V;  xRows=1024; wStride=256; wOff=0;   break;
      case 3: X=desc; W=eW1; bias=eb1;     out=ws+WS_AP; xRows=1020; wStride=512; wOff=0;   break;
      default:X=desc; W=eW1; bias=nullptr; out=ws+WS_BP; xRows=1020; wStride=512; wOff=256; break;
    }
    gemm_tile_512(X, xRows, W, wStride, wOff, 256, bias,
                  out, 256, xRows, 256, blockIdx.x*64, blockIdx.y*64);
}

// ---------------------------------------------------------------------------
// Kernel 2 (fused): z<4 transpose+rowstats(b=z) | z in 4..7: G gemm | z==8: prep
// grid (8,8,9), 512 threads
// ---------------------------------------------------------------------------
__global__ __launch_bounds__(512, 4) void fused_mid(
    const float* __restrict__ eW2, const float* __restrict__ eb2,
    const float* __restrict__ aW, float* __restrict__ ws)
{
    int z = blockIdx.z;
    int tid = threadIdx.x;
    if (z < 4) {
        // transpose/combine + row stats (atomic)
        __shared__ float tA[32][33], tB[32][33];
        int b = z;
        int j0 = blockIdx.x * 32;
        int k0 = blockIdx.y * 32;
        int lr = tid >> 5;    // 0..15
        int lc = tid & 31;
        #pragma unroll
        for (int t = 0; t < 2; t++) {
            int jj = lr + t*16;
            int j = j0 + jj;
            float av = 0.f, bv = 0.f;
            if (j < S) {
                av = ws[WS_AP + (b*S + j)*256 + k0 + lc];
                bv = ws[WS_BP + (b*S + j)*256 + k0 + lc];
            }
            tA[jj][lc] = av;
            tB[jj][lc] = bv;
        }
        __syncthreads();
        #pragma unroll
        for (int t = 0; t < 2; t++) {
            int kk = lr + t*16;
            int k = k0 + kk;
            int j = j0 + lc;
            float av = tA[lc][kk];
            float bv = tB[lc][kk];
            ws[WS_BT + (b*256 + k)*256 + j] = bv;
            ws[WS_CT + (b*256 + k)*256 + j] = av + bv;
        }
        if (tid < 32) {
            int jj = tid;
            float sa = 0.f, qa = 0.f, sb = 0.f, qb = 0.f;
            #pragma unroll 8
            for (int kk = 0; kk < 32; kk++) {
                float a = tA[jj][kk], bb = tB[jj][kk];
                sa += a;  qa = fmaf(a, a, qa);
                sb += bb; qb = fmaf(bb, bb, qb);
            }
            int j = j0 + jj;
            atomicAdd(&ws[WS_SA + b*256 + j], sa);
            atomicAdd(&ws[WS_QA + b*256 + j], qa);
            atomicAdd(&ws[WS_SB + b*256 + j], sb);
            atomicAdd(&ws[WS_QB + b*256 + j], qb);
        }
    } else if (z < 8) {
        int b = z - 4;
        if (blockIdx.x < 4 && blockIdx.y < 4) {
            gemm_tile_512(ws + WS_AP + b*S*256, 255,
                          ws + WS_BP + b*S*256, 256, 0, 255,
                          nullptr,
                          ws + WS_G + b*65536, 256, 255, 255,
                          blockIdx.x*64, blockIdx.y*64);
        }
    } else {
        int idx = blockIdx.y*8 + blockIdx.x;
        if (idx < 8) {
            if (tid < 256) {
                int h = idx;
                float acc = 0.f;
                #pragma unroll
                for (int hd = 0; hd < 32; hd++)
                    acc = fmaf(aW[64+hd], eW2[(h*32+hd)*256 + tid], acc);
                ws[WS_MT + tid*8 + h] = acc;
                if (tid == 0) {
                    float c = 0.f;
                    for (int hd = 0; hd < 32; hd++) c = fmaf(aW[64+hd], eb2[h*32+hd], c);
                    ws[WS_CH + h] = c;
                }
            }
        } else if (idx < 40) {
            if (tid < 256) {
                int p = idx - 8;
                int b = p >> 3, h = p & 7;
                const float* qrow = ws + WS_Q + (b*256 + tid)*256 + h*32;
                const float* krow = ws + WS_K + (b*256 + tid)*256 + h*32;
                float aq = 0.f, ak = 0.f;
                #pragma unroll
                for (int d4 = 0; d4 < 8; d4++) {
                    float4 qv = *(const float4*)&qrow[d4*4];
                    float4 wq = *(const float4*)&aW[d4*4];
                    float4 kv = *(const float4*)&krow[d4*4];
                    float4 wk = *(const float4*)&aW[32 + d4*4];
                    aq = fmaf(qv.x, wq.x, aq); aq = fmaf(qv.y, wq.y, aq);
                    aq = fmaf(qv.z, wq.z, aq); aq = fmaf(qv.w, wq.w, aq);
                    ak = fmaf(kv.x, wk.x, ak); ak = fmaf(kv.y, wk.y, ak);
                    ak = fmaf(kv.z, wk.z, ak); ak = fmaf(kv.w, wk.w, ak);
                }
                ws[WS_QLOG + (b*8+h)*256 + tid] = aq;
                ws[WS_KLOG + (b*8+h)*256 + tid] = ak;
            }
        }
    }
}

// ---------------------------------------------------------------------------
// Kernel 3: main.  block=(i,b), 512 threads: half=tid>>8 splits k-loop.
// ---------------------------------------------------------------------------
__global__ __launch_bounds__(512, 8) void main_kernel(
    const float* __restrict__ ln_g, const float* __restrict__ ln_b,
    const float* __restrict__ ab, const float* __restrict__ ws,
    float* __restrict__ out)
{
    int b = blockIdx.y;
    int i = blockIdx.x;
    int tid = threadIdx.x;
    int j = tid & 255;
    int half = tid >> 8;
    int m = j - 1;

    __shared__ float4 agb[256];       // {A'[i-1,k] (or 0), g_k, beta_k, 0}
    __shared__ float MtL[2048];       // [k][h]
    __shared__ float PL[8][256];      // logits -> p
    __shared__ float part[256][8];    // half1 partial head accs
    __shared__ float cpart[512];      // ctx partials
    __shared__ float mx[8], sm[8];

    if (tid < 256) {
        float aval = (i >= 1) ? ws[WS_AP + (b*S + (i-1))*256 + tid] : 0.f;
        agb[tid] = make_float4(aval, ln_g[tid], ln_b[tid], 0.f);
    } else {
        int t = tid - 256;
        float4 v0 = *(const float4*)&ws[WS_MT + t*8];
        float4 v1 = *(const float4*)&ws[WS_MT + t*8 + 4];
        *(float4*)&MtL[t*8]     = v0;
        *(float4*)&MtL[t*8 + 4] = v1;
    }
    __syncthreads();

    const float* colBase = ws + ((i >= 1) ? WS_BT : WS_CT) + b*65536;
    float acc[8] = {0,0,0,0,0,0,0,0};

    if (j >= 1) {
        float sa, qa, sb, qb, g;
        if (i >= 1) {
            int ii = i - 1;
            sa = ws[WS_SA + b*256 + ii]; qa = ws[WS_QA + b*256 + ii];
            sb = ws[WS_SB + b*256 + m];  qb = ws[WS_QB + b*256 + m];
            g  = ws[WS_G + (b*256 + ii)*256 + m];
        } else {
            sa = ws[WS_SA + b*256 + m];  qa = ws[WS_QA + b*256 + m];
            sb = ws[WS_SB + b*256 + m];  qb = ws[WS_QB + b*256 + m];
            g  = ws[WS_G + (b*256 + m)*256 + m];
        }
        float s1v = sa + sb;
        float s2v = qa + qb + 2.f*g;
        float mu  = s1v * (1.0f/256.0f);
        float var = s2v * (1.0f/256.0f) - mu*mu;
        float inv = rsqrtf(var + 1e-5f);
        float mus = mu * inv;
        int kb = half * 128;
        #pragma unroll 8
        for (int kk = 0; kk < 128; kk++) {
            int k = kb + kk;
            float4 u = agb[k];
            float t0 = colBase[k*256 + m] + u.x;
            float zz = fmaf(t0, inv, -mus);
            float w  = fmaf(zz, u.y, u.z);
            w = fmaxf(w, 0.f);
            float4 m0 = *(const float4*)&MtL[k*8];
            float4 m1 = *(const float4*)&MtL[k*8 + 4];
            acc[0] = fmaf(w, m0.x, acc[0]);
            acc[1] = fmaf(w, m0.y, acc[1]);
            acc[2] = fmaf(w, m0.z, acc[2]);
            acc[3] = fmaf(w, m0.w, acc[3]);
            acc[4] = fmaf(w, m1.x, acc[4]);
            acc[5] = fmaf(w, m1.y, acc[5]);
            acc[6] = fmaf(w, m1.z, acc[6]);
            acc[7] = fmaf(w, m1.w, acc[7]);
        }
    }

    if (half == 1) {
        *(float4*)&part[j][0] = make_float4(acc[0], acc[1], acc[2], acc[3]);
        *(float4*)&part[j][4] = make_float4(acc[4], acc[5], acc[6], acc[7]);
    }
    __syncthreads();

    if (half == 0) {
        float abv = ab[0];
        #pragma unroll
        for (int h = 0; h < 8; h++) {
            float base = ws[WS_QLOG + (b*8+h)*256 + i] + ws[WS_KLOG + (b*8+h)*256 + j] + abv;
            float l;
            if (j == 0) l = base - 1e9f;
            else        l = base + acc[h] + part[j][h] + ws[WS_CH + h];
            PL[h][j] = l;
        }
    }
    __syncthreads();

    if (tid < 256) {  // max per head
        int h = tid >> 5, sgl = tid & 31;
        float mval = -INFINITY;
        #pragma unroll
        for (int r = 0; r < 8; r++) mval = fmaxf(mval, PL[h][sgl + r*32]);
        #pragma unroll
        for (int off = 16; off >= 1; off >>= 1)
            mval = fmaxf(mval, __shfl_xor(mval, off, 64));
        if (sgl == 0) mx[h] = mval;
    }
    __syncthreads();

    float p[8];
    if (half == 0) {
        #pragma unroll
        for (int h = 0; h < 8; h++) p[h] = expf(PL[h][j] - mx[h]);
    }
    __syncthreads();
    if (half == 0) {
        #pragma unroll
        for (int h = 0; h < 8; h++) PL[h][j] = p[h];
    }
    __syncthreads();

    if (tid < 256) {  // sum per head
        int h = tid >> 5, sgl = tid & 31;
        float sv = 0.f;
        #pragma unroll
        for (int r = 0; r < 8; r++) sv += PL[h][sgl + r*32];
        #pragma unroll
        for (int off = 16; off >= 1; off >>= 1)
            sv += __shfl_xor(sv, off, 64);
        if (sgl == 0) sm[h] = sv;
    }
    __syncthreads();

    // attn output
    if (half == 0) {
        float* attnOut = out + B*S1*D;
        #pragma unroll
        for (int h = 0; h < 8; h++)
            attnOut[((b*8+h)*256 + i)*256 + j] = p[h] / sm[h];
    }

    // ctx: col = j target output column; split jj over halves
    {
        int col = j;
        int h = col >> 5;
        const float* v = ws + WS_V + b*65536;
        int jb = half * 128;
        float c0 = 0.f;
        #pragma unroll 8
        for (int t = 0; t < 128; t++)
            c0 = fmaf(PL[h][jb + t], v[(jb + t)*256 + col], c0);
        cpart[tid] = c0;
    }
    __syncthreads();
    if (half == 0) {
        int h = j >> 5;
        out[(b*256 + i)*256 + j] = (cpart[tid] + cpart[tid + 256]) * (1.0f / sm[h]);
    }
}

// ---------------------------------------------------------------------------
extern "C" void kernel_launch(void* const* d_in, const int* in_sizes, int n_in,
                              void* d_out, int out_size, void* d_ws, size_t ws_size,
                              hipStream_t stream)
{
    const float* desc = (const float*)d_in[0];
    const float* nve  = (const float*)d_in[1];
    const float* qW   = (const float*)d_in[2];
    const float* qb   = (const float*)d_in[3];
    const float* kW   = (const float*)d_in[4];
    const float* kb   = (const float*)d_in[5];
    const float* vW   = (const float*)d_in[6];
    const float* vb   = (const float*)d_in[7];
    const float* eW1  = (const float*)d_in[8];
    const float* eb1  = (const float*)d_in[9];
    const float* ln_g = (const float*)d_in[10];
    const float* ln_b = (const float*)d_in[11];
    const float* eW2  = (const float*)d_in[12];
    const float* eb2  = (const float*)d_in[13];
    const float* aW   = (const float*)d_in[14];
    const float* ab   = (const float*)d_in[15];
    float* ws  = (float*)d_ws;
    float* out = (float*)d_out;

    // zero the atomic row-stat accumulators (SA..QB contiguous, 4096 floats)
    hipMemsetAsync((char*)d_ws + (size_t)WS_SA*4, 0, 4096*4, stream);

    gemm_qkvAB<<<dim3(16, 4, 5), 512, 0, stream>>>(desc, nve, qW, qb, kW, kb, vW, vb, eW1, eb1, ws);
    fused_mid <<<dim3(8, 8, 9), 512, 0, stream>>>(eW2, eb2, aW, ws);
    main_kernel<<<dim3(256, 4), 512, 0, stream>>>(ln_g, ln_b, ab, ws, out);
}